// Round 1
// baseline (3079.986 us; speedup 1.0000x reference)
//
#include <hip/hip_runtime.h>

// ---------------------------------------------------------------------------
// Transformer decoder fwd, bf16-MFMA compute, fp32 residual stream in d_out.
// L=8 B=4 S=1024 D=1024 H=16 dh=64 FC=4096. Threshold 0.1 allows bf16 GEMMs.
// ---------------------------------------------------------------------------

typedef __bf16 bf16x8 __attribute__((ext_vector_type(8)));
typedef float  f32x4  __attribute__((ext_vector_type(4)));

#define DEV static __device__ __forceinline__

DEV unsigned short f2bf(float x) {
  unsigned u = __builtin_bit_cast(unsigned int, x);
  u += 0x7fffu + ((u >> 16) & 1u);          // RNE
  return (unsigned short)(u >> 16);
}

DEV f32x4 mfma16(bf16x8 a, bf16x8 b, f32x4 c) {
  return __builtin_amdgcn_mfma_f32_16x16x32_bf16(a, b, c, 0, 0, 0);
}

DEV void gload_lds16(const unsigned short* g, unsigned short* l) {
  // async global->LDS, 16B/lane; LDS dest = wave-uniform base + lane*16
  __builtin_amdgcn_global_load_lds(
      (const __attribute__((address_space(1))) void*)g,
      (__attribute__((address_space(3))) void*)l, 16, 0, 0);
}

// ---------------------------------------------------------------------------
// fp32 [K][N] -> bf16 [N][K] transposed convert (32x32 LDS tile)
// grid = (K/32, N/32), block = 256
// ---------------------------------------------------------------------------
__global__ void transpose_cvt(const float* __restrict__ src,
                              unsigned short* __restrict__ dst,
                              int srcStride, int dstStride) {
  __shared__ float tile[32][33];
  const int t  = threadIdx.x;
  const int r  = t >> 3;
  const int c4 = (t & 7) << 2;
  const int k  = blockIdx.x * 32 + r;
  const int n0 = blockIdx.y * 32 + c4;
  const float4 v = *reinterpret_cast<const float4*>(src + (size_t)k * srcStride + n0);
  tile[r][c4] = v.x; tile[r][c4 + 1] = v.y; tile[r][c4 + 2] = v.z; tile[r][c4 + 3] = v.w;
  __syncthreads();
  const int n  = blockIdx.y * 32 + r;
  const int k0 = blockIdx.x * 32 + c4;
  ushort4 o;
  o.x = f2bf(tile[c4][r]);     o.y = f2bf(tile[c4 + 1][r]);
  o.z = f2bf(tile[c4 + 2][r]); o.w = f2bf(tile[c4 + 3][r]);
  *reinterpret_cast<ushort4*>(dst + (size_t)n * dstStride + k0) = o;
}

__global__ void pack_qkv_bias(const float* __restrict__ bq, const float* __restrict__ bk,
                              const float* __restrict__ bv, float* __restrict__ out) {
  int i = blockIdx.x * 256 + threadIdx.x;   // 3072
  out[i] = (i < 1024) ? bq[i] : (i < 2048 ? bk[i - 1024] : bv[i - 2048]);
}

// ---------------------------------------------------------------------------
// LayerNorm: one block per row (D=1024, 256 thr x 4 elems). OUTF32: fp32 out
// (final LN, may be in-place on x); else bf16 out.
// ---------------------------------------------------------------------------
template <int OUTF32>
__global__ void ln_kernel(const float* x, const float* __restrict__ gam,
                          const float* __restrict__ bet, void* out) {
  const int row = blockIdx.x;
  const int t   = threadIdx.x;
  const float* xr = x + (size_t)row * 1024;
  const float4 v = *reinterpret_cast<const float4*>(xr + t * 4);
  float s  = v.x + v.y + v.z + v.w;
  float ss = v.x * v.x + v.y * v.y + v.z * v.z + v.w * v.w;
  #pragma unroll
  for (int m = 32; m; m >>= 1) { s += __shfl_xor(s, m); ss += __shfl_xor(ss, m); }
  __shared__ float red[8];
  const int wv = t >> 6, ln = t & 63;
  if (ln == 0) { red[wv] = s; red[4 + wv] = ss; }
  __syncthreads();
  s  = red[0] + red[1] + red[2] + red[3];
  ss = red[4] + red[5] + red[6] + red[7];
  const float mean = s * (1.0f / 1024.0f);
  const float var  = ss * (1.0f / 1024.0f) - mean * mean;
  const float rstd = rsqrtf(var + 1e-5f);
  const float4 g  = *reinterpret_cast<const float4*>(gam + t * 4);
  const float4 bb = *reinterpret_cast<const float4*>(bet + t * 4);
  const float y0 = (v.x - mean) * rstd * g.x + bb.x;
  const float y1 = (v.y - mean) * rstd * g.y + bb.y;
  const float y2 = (v.z - mean) * rstd * g.z + bb.z;
  const float y3 = (v.w - mean) * rstd * g.w + bb.w;
  if (OUTF32) {
    float4 o; o.x = y0; o.y = y1; o.z = y2; o.w = y3;
    *reinterpret_cast<float4*>((float*)out + (size_t)row * 1024 + t * 4) = o;
  } else {
    ushort4 o; o.x = f2bf(y0); o.y = f2bf(y1); o.z = f2bf(y2); o.w = f2bf(y3);
    *reinterpret_cast<ushort4*>((unsigned short*)out + (size_t)row * 1024 + t * 4) = o;
  }
}

// ---------------------------------------------------------------------------
// GEMM: C[M][N] = A[M][K](bf16) * Bt[N][K]^T(bf16) + bias.
// m97 structure: 128 x BN tile, BK=32, 4 waves (2x2), global_load_lds x16B.
// MODE 0: bf16 out; MODE 1: gelu(erf) -> bf16; MODE 2: xout = xin + scl*C (f32)
// grid = (M/128, N/BN), block = 256
// ---------------------------------------------------------------------------
template <int MODE, int BN>
__global__ __launch_bounds__(256) void gemm_k(
    const unsigned short* __restrict__ A, const unsigned short* __restrict__ Bt,
    const float* __restrict__ bias, unsigned short* __restrict__ outb,
    const float* xin, float* xout, const float* __restrict__ scale_p,
    int N, int K) {
  constexpr int NI = BN / 32;                 // n-frags per wave
  __shared__ __attribute__((aligned(16))) unsigned short As[128 * 32];
  __shared__ __attribute__((aligned(16))) unsigned short Bs[BN * 32];
  const int t = threadIdx.x, wave = t >> 6, lane = t & 63;
  const int m0 = blockIdx.x * 128, n0 = blockIdx.y * BN;
  const int wm = wave >> 1, wn = wave & 1;

  const int ldr = lane >> 2;                  // row-in-chunk 0..15
  const int kc  = (lane & 3) * 8;             // k offset 0/8/16/24

  const unsigned short* gA0 = A + (size_t)(m0 + wave * 32 + ldr) * K + kc;
  const unsigned short* gA1 = gA0 + (size_t)16 * K;
  unsigned short* lA0 = &As[wave * 1024];
  unsigned short* lA1 = lA0 + 512;

  const unsigned short* gB0;
  const unsigned short* gB1 = nullptr;
  unsigned short *lB0, *lB1 = nullptr;
  if constexpr (BN == 128) {
    gB0 = Bt + (size_t)(n0 + wave * 32 + ldr) * K + kc;
    gB1 = gB0 + (size_t)16 * K;
    lB0 = &Bs[wave * 1024];
    lB1 = lB0 + 512;
  } else {
    gB0 = Bt + (size_t)(n0 + wave * 16 + ldr) * K + kc;
    lB0 = &Bs[wave * 512];
  }

  const int a_off = (wm * 64 + (lane & 15)) * 32 + (lane >> 4) * 8;
  const int b_off = (wn * (BN / 2) + (lane & 15)) * 32 + (lane >> 4) * 8;

  f32x4 acc[4][NI] = {};

  const int nk = K >> 5;
  for (int kt = 0; kt < nk; ++kt) {
    const int ko = kt * 32;
    gload_lds16(gA0 + ko, lA0);
    gload_lds16(gA1 + ko, lA1);
    gload_lds16(gB0 + ko, lB0);
    if constexpr (BN == 128) gload_lds16(gB1 + ko, lB1);
    __syncthreads();                           // waits vmcnt(0): tiles landed
    bf16x8 a[4], bfr[NI];
    #pragma unroll
    for (int i = 0; i < 4; ++i)
      a[i] = *reinterpret_cast<const bf16x8*>(&As[a_off + i * 512]);
    #pragma unroll
    for (int i = 0; i < NI; ++i)
      bfr[i] = *reinterpret_cast<const bf16x8*>(&Bs[b_off + i * 512]);
    #pragma unroll
    for (int mi = 0; mi < 4; ++mi)
      #pragma unroll
      for (int ni = 0; ni < NI; ++ni)
        acc[mi][ni] = mfma16(a[mi], bfr[ni], acc[mi][ni]);
    __syncthreads();                           // compute done before overwrite
  }

  const int mrow = m0 + wm * 64 + (lane >> 4) * 4;
  const int ncol = n0 + wn * (BN / 2) + (lane & 15);
  float scl = 0.f;
  if constexpr (MODE == 2) scl = scale_p[0];
  #pragma unroll
  for (int ni = 0; ni < NI; ++ni) {
    const int n = ncol + ni * 16;
    const float bn = bias[n];
    #pragma unroll
    for (int mi = 0; mi < 4; ++mi) {
      #pragma unroll
      for (int r = 0; r < 4; ++r) {
        const size_t idx = (size_t)(mrow + mi * 16 + r) * N + n;
        float v = acc[mi][ni][r] + bn;
        if constexpr (MODE == 0) {
          outb[idx] = f2bf(v);
        } else if constexpr (MODE == 1) {
          v = 0.5f * v * (1.0f + erff(v * 0.70710678118f));  // exact GELU
          outb[idx] = f2bf(v);
        } else {
          xout[idx] = xin[idx] + scl * v;      // re-zero residual, fp32
        }
      }
    }
  }
}

// ---------------------------------------------------------------------------
// V transpose: qkv v-part [b][s][h][d] -> vT [b][h][d][s] (bf16)
// grid = B*H*(S/64) = 1024, block = 256 (tile: 64 s x 64 d)
// ---------------------------------------------------------------------------
__global__ void v_transpose(const unsigned short* __restrict__ qkv,
                            unsigned short* __restrict__ vT) {
  const int bid = blockIdx.x;
  const int st = bid & 15, bh = bid >> 4;
  const int b = bh >> 4, h = bh & 15;
  const int t = threadIdx.x;
  const int d = t >> 2, s8 = (t & 3) << 4;    // 16 s-positions per thread
  const unsigned short* src =
      qkv + 2048 + (size_t)h * 64 + d + (size_t)(b * 1024 + st * 64 + s8) * 3072;
  alignas(16) unsigned short buf[16];
  #pragma unroll
  for (int i = 0; i < 16; ++i) buf[i] = src[(size_t)i * 3072];
  unsigned short* dst =
      vT + ((size_t)(b * 16 + h) * 64 + d) * 1024 + st * 64 + s8;
  *reinterpret_cast<uint4*>(dst)     = *reinterpret_cast<const uint4*>(buf);
  *reinterpret_cast<uint4*>(dst + 8) = *reinterpret_cast<const uint4*>(buf + 8);
}

// ---------------------------------------------------------------------------
// Flash attention, causal. grid = B*H*(S/64) = 1024, block = 256 (4 waves).
// Wave owns 16 q-rows; KV tiles of 32; online softmax fp32; P via LDS bounce.
// Q/K direct from qkv (bf16), V from vT. Out: vals [b][s][h*64+d] bf16.
// ---------------------------------------------------------------------------
__global__ __launch_bounds__(256) void attn_kernel(
    const unsigned short* __restrict__ qkv, const unsigned short* __restrict__ vT,
    unsigned short* __restrict__ vals) {
  const int bid = blockIdx.x;
  const int qt = bid & 15, bh = bid >> 4;
  const int b = bh >> 4, h = bh & 15;
  const int t = threadIdx.x, wave = t >> 6, lane = t & 63;
  const int q0 = qt * 64 + wave * 16;
  const int rowLane = lane & 15, grp = lane >> 4;

  __shared__ __attribute__((aligned(16))) unsigned short P_lds[4][512];  // 16x32 per wave

  const unsigned short* qbase =
      qkv + (size_t)(b * 1024 + q0 + rowLane) * 3072 + h * 64 + grp * 8;
  const bf16x8 aq0 = *reinterpret_cast<const bf16x8*>(qbase);
  const bf16x8 aq1 = *reinterpret_cast<const bf16x8*>(qbase + 32);

  f32x4 oacc[4] = {};
  float mrun[4], lrun[4];
  #pragma unroll
  for (int r = 0; r < 4; ++r) { mrun[r] = -1e30f; lrun[r] = 0.f; }

  const int tEnd = ((q0 + 15) >> 5) + 1;
  for (int kt = 0; kt < tEnd; ++kt) {
    const int kv0 = kt * 32;
    // ---- S = (Q K^T) * 1/8 ----
    f32x4 sacc[2];
    #pragma unroll
    for (int nf = 0; nf < 2; ++nf) {
      const unsigned short* kb =
          qkv + (size_t)(b * 1024 + kv0 + nf * 16 + rowLane) * 3072 + 1024 + h * 64 + grp * 8;
      const bf16x8 bk0 = *reinterpret_cast<const bf16x8*>(kb);
      const bf16x8 bk1 = *reinterpret_cast<const bf16x8*>(kb + 32);
      f32x4 z = {0.f, 0.f, 0.f, 0.f};
      z = mfma16(aq0, bk0, z);
      z = mfma16(aq1, bk1, z);
      sacc[nf] = z;
    }
    // ---- mask + online softmax ----
    float pv[2][4], mx[4];
    #pragma unroll
    for (int r = 0; r < 4; ++r) {
      const int qg = q0 + grp * 4 + r;
      float s0 = sacc[0][r] * 0.125f; if (kv0 + rowLane > qg)      s0 = -1e30f;
      float s1 = sacc[1][r] * 0.125f; if (kv0 + 16 + rowLane > qg) s1 = -1e30f;
      pv[0][r] = s0; pv[1][r] = s1;
      mx[r] = fmaxf(s0, s1);
    }
    #pragma unroll
    for (int m = 1; m <= 8; m <<= 1)
      #pragma unroll
      for (int r = 0; r < 4; ++r) mx[r] = fmaxf(mx[r], __shfl_xor(mx[r], m));
    float fac[4], rs[4];
    #pragma unroll
    for (int r = 0; r < 4; ++r) {
      const float mnew = fmaxf(mrun[r], mx[r]);
      fac[r] = __expf(mrun[r] - mnew);
      mrun[r] = mnew;
      const float p0 = __expf(pv[0][r] - mnew);
      const float p1 = __expf(pv[1][r] - mnew);
      pv[0][r] = p0; pv[1][r] = p1;
      rs[r] = p0 + p1;
    }
    #pragma unroll
    for (int m = 1; m <= 8; m <<= 1)
      #pragma unroll
      for (int r = 0; r < 4; ++r) rs[r] += __shfl_xor(rs[r], m);
    #pragma unroll
    for (int r = 0; r < 4; ++r) lrun[r] = lrun[r] * fac[r] + rs[r];
    #pragma unroll
    for (int nf = 0; nf < 4; ++nf)
      #pragma unroll
      for (int r = 0; r < 4; ++r) oacc[nf][r] *= fac[r];
    // ---- P -> bf16 -> LDS (C-layout -> A-layout bounce, per-wave) ----
    unsigned short* P = P_lds[wave];
    #pragma unroll
    for (int nf = 0; nf < 2; ++nf)
      #pragma unroll
      for (int r = 0; r < 4; ++r)
        P[(grp * 4 + r) * 32 + nf * 16 + rowLane] = f2bf(pv[nf][r]);
    const bf16x8 pa = *reinterpret_cast<const bf16x8*>(&P[rowLane * 32 + grp * 8]);
    // ---- O += P V ----
    #pragma unroll
    for (int nf = 0; nf < 4; ++nf) {
      const unsigned short* vb =
          vT + ((size_t)(b * 16 + h) * 64 + nf * 16 + rowLane) * 1024 + kv0 + grp * 8;
      const bf16x8 bv = *reinterpret_cast<const bf16x8*>(vb);
      oacc[nf] = mfma16(pa, bv, oacc[nf]);
    }
  }
  // ---- epilogue: O / l ----
  #pragma unroll
  for (int nf = 0; nf < 4; ++nf)
    #pragma unroll
    for (int r = 0; r < 4; ++r) {
      const int qg = q0 + grp * 4 + r;
      const float v = oacc[nf][r] / lrun[r];
      vals[(size_t)(b * 1024 + qg) * 1024 + h * 64 + nf * 16 + rowLane] = f2bf(v);
    }
}

// ---------------------------------------------------------------------------
extern "C" void kernel_launch(void* const* d_in, const int* in_sizes, int n_in,
                              void* d_out, int out_size, void* d_ws, size_t ws_size,
                              hipStream_t stream) {
  (void)in_sizes; (void)n_in; (void)out_size; (void)ws_size;
  const float* inputs = (const float*)d_in[0];
  const float* Wq = (const float*)d_in[1];  const float* bq = (const float*)d_in[2];
  const float* Wk = (const float*)d_in[3];  const float* bk = (const float*)d_in[4];
  const float* Wv = (const float*)d_in[5];  const float* bv = (const float*)d_in[6];
  const float* Wo = (const float*)d_in[7];  const float* bo = (const float*)d_in[8];
  const float* W1 = (const float*)d_in[9];  const float* b1 = (const float*)d_in[10];
  const float* W2 = (const float*)d_in[11]; const float* b2 = (const float*)d_in[12];
  const float* ln_g = (const float*)d_in[13];
  const float* ln_b = (const float*)d_in[14];
  const float* scale_p = (const float*)d_in[15];
  float* xbuf = (float*)d_out;               // fp32 residual stream lives here

  char* w = (char*)d_ws;
  size_t off = 0;
  auto take = [&](size_t bytes) {
    void* p = w + off;
    off = (off + bytes + 255) & ~(size_t)255;
    return p;
  };
  unsigned short* Wqkv_t = (unsigned short*)take((size_t)3072 * 1024 * 2);  // [3072][1024]
  unsigned short* Wo_t   = (unsigned short*)take((size_t)1024 * 1024 * 2);  // [1024][1024]
  unsigned short* W1_t   = (unsigned short*)take((size_t)4096 * 1024 * 2);  // [4096][1024]
  unsigned short* W2_t   = (unsigned short*)take((size_t)1024 * 4096 * 2);  // [1024][4096]
  float*          bqkv   = (float*)take(3072 * 4);
  unsigned short* rbuf   = (unsigned short*)take((size_t)4096 * 1024 * 2);  // LN out
  unsigned short* qkvb   = (unsigned short*)take((size_t)4096 * 3072 * 2);  // q|k|v
  unsigned short* vTb    = (unsigned short*)take((size_t)64 * 64 * 1024 * 2);
  unsigned short* valsb  = (unsigned short*)take((size_t)4096 * 1024 * 2);
  unsigned short* hbuf   = (unsigned short*)take((size_t)4096 * 4096 * 2);  // FFN hidden
  // total ~109 MB

  for (int i = 0; i < 8; ++i) {
    const float* xin = (i == 0) ? inputs : xbuf;
    // weights -> bf16, transposed [N][K]
    transpose_cvt<<<dim3(32, 32), 256, 0, stream>>>(Wq + (size_t)i * 1024 * 1024, Wqkv_t, 1024, 1024);
    transpose_cvt<<<dim3(32, 32), 256, 0, stream>>>(Wk + (size_t)i * 1024 * 1024, Wqkv_t + 1024 * 1024, 1024, 1024);
    transpose_cvt<<<dim3(32, 32), 256, 0, stream>>>(Wv + (size_t)i * 1024 * 1024, Wqkv_t + 2 * 1024 * 1024, 1024, 1024);
    transpose_cvt<<<dim3(32, 32), 256, 0, stream>>>(Wo + (size_t)i * 1024 * 1024, Wo_t, 1024, 1024);
    transpose_cvt<<<dim3(32, 128), 256, 0, stream>>>(W1 + (size_t)i * 1024 * 4096, W1_t, 4096, 1024);
    transpose_cvt<<<dim3(128, 32), 256, 0, stream>>>(W2 + (size_t)i * 4096 * 1024, W2_t, 1024, 4096);
    pack_qkv_bias<<<12, 256, 0, stream>>>(bq + i * 1024, bk + i * 1024, bv + i * 1024, bqkv);
    // attention block
    ln_kernel<0><<<4096, 256, 0, stream>>>(xin, ln_g, ln_b, rbuf);
    gemm_k<0, 128><<<dim3(32, 24), 256, 0, stream>>>(rbuf, Wqkv_t, bqkv, qkvb,
                                                     nullptr, nullptr, nullptr, 3072, 1024);
    v_transpose<<<1024, 256, 0, stream>>>(qkvb, vTb);
    attn_kernel<<<1024, 256, 0, stream>>>(qkvb, vTb, valsb);
    gemm_k<2, 64><<<dim3(32, 16), 256, 0, stream>>>(valsb, Wo_t, bo + i * 1024, nullptr,
                                                    xin, xbuf, scale_p, 1024, 1024);
    // FFN block
    ln_kernel<0><<<4096, 256, 0, stream>>>(xbuf, ln_g, ln_b, rbuf);
    gemm_k<1, 128><<<dim3(32, 32), 256, 0, stream>>>(rbuf, W1_t, b1 + i * 4096, hbuf,
                                                     nullptr, nullptr, nullptr, 4096, 1024);
    gemm_k<2, 64><<<dim3(32, 16), 256, 0, stream>>>(hbuf, W2_t, b2 + i * 1024, nullptr,
                                                    xbuf, xbuf, scale_p, 1024, 4096);
  }
  ln_kernel<1><<<4096, 256, 0, stream>>>(xbuf, ln_g, ln_b, xbuf);  // final LN, in-place
}

// Round 2
// 3079.362 us; speedup vs baseline: 1.0002x; 1.0002x over previous
//
#include <hip/hip_runtime.h>

// ---------------------------------------------------------------------------
// Transformer decoder fwd, bf16-MFMA compute, fp32 residual stream in d_out.
// L=8 B=4 S=1024 D=1024 H=16 dh=64 FC=4096. Threshold 0.1 allows bf16 GEMMs.
// ---------------------------------------------------------------------------

typedef __bf16 bf16x8 __attribute__((ext_vector_type(8)));
typedef float  f32x4  __attribute__((ext_vector_type(4)));

#define DEV static __device__ __forceinline__

DEV unsigned short f2bf(float x) {
  unsigned u = __builtin_bit_cast(unsigned int, x);
  u += 0x7fffu + ((u >> 16) & 1u);          // RNE
  return (unsigned short)(u >> 16);
}

DEV f32x4 mfma16(bf16x8 a, bf16x8 b, f32x4 c) {
  return __builtin_amdgcn_mfma_f32_16x16x32_bf16(a, b, c, 0, 0, 0);
}

DEV bf16x8 ldb8(const unsigned short* p) {
  return *reinterpret_cast<const bf16x8*>(p);
}

DEV void gload_lds16(const unsigned short* g, unsigned short* l) {
  // async global->LDS, 16B/lane; LDS dest = wave-uniform base + lane*16
  __builtin_amdgcn_global_load_lds(
      (const __attribute__((address_space(1))) void*)g,
      (__attribute__((address_space(3))) void*)l, 16, 0, 0);
}

// ---------------------------------------------------------------------------
// fp32 [K][N] -> bf16 [N][K] transposed convert (32x32 LDS tile)
// grid = (K/32, N/32), block = 256
// ---------------------------------------------------------------------------
__global__ void transpose_cvt(const float* __restrict__ src,
                              unsigned short* __restrict__ dst,
                              int srcStride, int dstStride) {
  __shared__ float tile[32][33];
  const int t  = threadIdx.x;
  const int r  = t >> 3;
  const int c4 = (t & 7) << 2;
  const int k  = blockIdx.x * 32 + r;
  const int n0 = blockIdx.y * 32 + c4;
  const float4 v = *reinterpret_cast<const float4*>(src + (size_t)k * srcStride + n0);
  tile[r][c4] = v.x; tile[r][c4 + 1] = v.y; tile[r][c4 + 2] = v.z; tile[r][c4 + 3] = v.w;
  __syncthreads();
  const int n  = blockIdx.y * 32 + r;
  const int k0 = blockIdx.x * 32 + c4;
  ushort4 o;
  o.x = f2bf(tile[c4][r]);     o.y = f2bf(tile[c4 + 1][r]);
  o.z = f2bf(tile[c4 + 2][r]); o.w = f2bf(tile[c4 + 3][r]);
  *reinterpret_cast<ushort4*>(dst + (size_t)n * dstStride + k0) = o;
}

__global__ void pack_qkv_bias(const float* __restrict__ bq, const float* __restrict__ bk,
                              const float* __restrict__ bv, float* __restrict__ out) {
  int i = blockIdx.x * 256 + threadIdx.x;   // 3072
  out[i] = (i < 1024) ? bq[i] : (i < 2048 ? bk[i - 1024] : bv[i - 2048]);
}

// ---------------------------------------------------------------------------
// LayerNorm: one block per row (D=1024, 256 thr x 4 elems). OUTF32: fp32 out
// ---------------------------------------------------------------------------
template <int OUTF32>
__global__ void ln_kernel(const float* x, const float* __restrict__ gam,
                          const float* __restrict__ bet, void* out) {
  const int row = blockIdx.x;
  const int t   = threadIdx.x;
  const float* xr = x + (size_t)row * 1024;
  const float4 v = *reinterpret_cast<const float4*>(xr + t * 4);
  float s  = v.x + v.y + v.z + v.w;
  float ss = v.x * v.x + v.y * v.y + v.z * v.z + v.w * v.w;
  #pragma unroll
  for (int m = 32; m; m >>= 1) { s += __shfl_xor(s, m); ss += __shfl_xor(ss, m); }
  __shared__ float red[8];
  const int wv = t >> 6, ln = t & 63;
  if (ln == 0) { red[wv] = s; red[4 + wv] = ss; }
  __syncthreads();
  s  = red[0] + red[1] + red[2] + red[3];
  ss = red[4] + red[5] + red[6] + red[7];
  const float mean = s * (1.0f / 1024.0f);
  const float var  = ss * (1.0f / 1024.0f) - mean * mean;
  const float rstd = rsqrtf(var + 1e-5f);
  const float4 g  = *reinterpret_cast<const float4*>(gam + t * 4);
  const float4 bb = *reinterpret_cast<const float4*>(bet + t * 4);
  const float y0 = (v.x - mean) * rstd * g.x + bb.x;
  const float y1 = (v.y - mean) * rstd * g.y + bb.y;
  const float y2 = (v.z - mean) * rstd * g.z + bb.z;
  const float y3 = (v.w - mean) * rstd * g.w + bb.w;
  if (OUTF32) {
    float4 o; o.x = y0; o.y = y1; o.z = y2; o.w = y3;
    *reinterpret_cast<float4*>((float*)out + (size_t)row * 1024 + t * 4) = o;
  } else {
    ushort4 o; o.x = f2bf(y0); o.y = f2bf(y1); o.z = f2bf(y2); o.w = f2bf(y3);
    *reinterpret_cast<ushort4*>((unsigned short*)out + (size_t)row * 1024 + t * 4) = o;
  }
}

// ---------------------------------------------------------------------------
// GEMM: C[M][N] = A[M][K](bf16) * Bt[N][K]^T(bf16) + bias.
// m97 structure: 128 x BN tile, BK=32, 4 waves (2x2), global_load_lds x16B.
// MODE 0: bf16 out; MODE 1: gelu(erf) -> bf16; MODE 2: xout = xin + scl*C (f32)
// grid = (M/128, N/BN), block = 256
// ---------------------------------------------------------------------------
template <int MODE, int BN>
__global__ __launch_bounds__(256) void gemm_k(
    const unsigned short* __restrict__ A, const unsigned short* __restrict__ Bt,
    const float* __restrict__ bias, unsigned short* __restrict__ outb,
    const float* xin, float* xout, const float* __restrict__ scale_p,
    int N, int K) {
  constexpr int NI = BN / 32;                 // n-frags per wave
  __shared__ __attribute__((aligned(16))) unsigned short As[128 * 32];
  __shared__ __attribute__((aligned(16))) unsigned short Bs[BN * 32];
  const int t = threadIdx.x, wave = t >> 6, lane = t & 63;
  const int m0 = blockIdx.x * 128, n0 = blockIdx.y * BN;
  const int wm = wave >> 1, wn = wave & 1;

  const int ldr = lane >> 2;                  // row-in-chunk 0..15
  const int kc  = (lane & 3) * 8;             // k offset 0/8/16/24

  const unsigned short* gA0 = A + (size_t)(m0 + wave * 32 + ldr) * K + kc;
  const unsigned short* gA1 = gA0 + (size_t)16 * K;
  unsigned short* lA0 = &As[wave * 1024];
  unsigned short* lA1 = lA0 + 512;

  const unsigned short* gB0;
  const unsigned short* gB1 = nullptr;
  unsigned short *lB0, *lB1 = nullptr;
  if constexpr (BN == 128) {
    gB0 = Bt + (size_t)(n0 + wave * 32 + ldr) * K + kc;
    gB1 = gB0 + (size_t)16 * K;
    lB0 = &Bs[wave * 1024];
    lB1 = lB0 + 512;
  } else {
    gB0 = Bt + (size_t)(n0 + wave * 16 + ldr) * K + kc;
    lB0 = &Bs[wave * 512];
  }

  const int a_off = (wm * 64 + (lane & 15)) * 32 + (lane >> 4) * 8;
  const int b_off = (wn * (BN / 2) + (lane & 15)) * 32 + (lane >> 4) * 8;

  f32x4 acc[4][NI] = {};

  const int nk = K >> 5;
  for (int kt = 0; kt < nk; ++kt) {
    const int ko = kt * 32;
    gload_lds16(gA0 + ko, lA0);
    gload_lds16(gA1 + ko, lA1);
    gload_lds16(gB0 + ko, lB0);
    if constexpr (BN == 128) gload_lds16(gB1 + ko, lB1);
    __syncthreads();                           // waits vmcnt(0): tiles landed
    bf16x8 a[4], bfr[NI];
    #pragma unroll
    for (int i = 0; i < 4; ++i)
      a[i] = *reinterpret_cast<const bf16x8*>(&As[a_off + i * 512]);
    #pragma unroll
    for (int i = 0; i < NI; ++i)
      bfr[i] = *reinterpret_cast<const bf16x8*>(&Bs[b_off + i * 512]);
    #pragma unroll
    for (int mi = 0; mi < 4; ++mi)
      #pragma unroll
      for (int ni = 0; ni < NI; ++ni)
        acc[mi][ni] = mfma16(a[mi], bfr[ni], acc[mi][ni]);
    __syncthreads();                           // compute done before overwrite
  }

  const int mrow = m0 + wm * 64 + (lane >> 4) * 4;
  const int ncol = n0 + wn * (BN / 2) + (lane & 15);
  float scl = 0.f;
  if constexpr (MODE == 2) scl = scale_p[0];
  #pragma unroll
  for (int ni = 0; ni < NI; ++ni) {
    const int n = ncol + ni * 16;
    const float bn = bias[n];
    #pragma unroll
    for (int mi = 0; mi < 4; ++mi) {
      #pragma unroll
      for (int r = 0; r < 4; ++r) {
        const size_t idx = (size_t)(mrow + mi * 16 + r) * N + n;
        float v = acc[mi][ni][r] + bn;
        if constexpr (MODE == 0) {
          outb[idx] = f2bf(v);
        } else if constexpr (MODE == 1) {
          v = 0.5f * v * (1.0f + erff(v * 0.70710678118f));  // exact GELU
          outb[idx] = f2bf(v);
        } else {
          xout[idx] = xin[idx] + scl * v;      // re-zero residual, fp32
        }
      }
    }
  }
}

// ---------------------------------------------------------------------------
// V transpose: qkv v-part [b][s][h][d] -> vT [b][h][d][s] (bf16)
// grid = B*H*(S/64) = 1024, block = 256 (tile: 64 s x 64 d)
// ---------------------------------------------------------------------------
__global__ void v_transpose(const unsigned short* __restrict__ qkv,
                            unsigned short* __restrict__ vT) {
  const int bid = blockIdx.x;
  const int st = bid & 15, bh = bid >> 4;
  const int b = bh >> 4, h = bh & 15;
  const int t = threadIdx.x;
  const int d = t >> 2, s8 = (t & 3) << 4;    // 16 s-positions per thread
  const unsigned short* src =
      qkv + 2048 + (size_t)h * 64 + d + (size_t)(b * 1024 + st * 64 + s8) * 3072;
  alignas(16) unsigned short buf[16];
  #pragma unroll
  for (int i = 0; i < 16; ++i) buf[i] = src[(size_t)i * 3072];
  unsigned short* dst =
      vT + ((size_t)(b * 16 + h) * 64 + d) * 1024 + st * 64 + s8;
  *reinterpret_cast<uint4*>(dst)     = *reinterpret_cast<const uint4*>(buf);
  *reinterpret_cast<uint4*>(dst + 8) = *reinterpret_cast<const uint4*>(buf + 8);
}

// ---------------------------------------------------------------------------
// Flash attention v2, causal. grid = 1024, block = 256 (4 waves).
// Pairing: dispatch pair (2p, 2p+1) -> q-tiles (7-tp, 8+tp) of head bh=p&63
//   -> constant work per pair (tail kill) + per-head XCD locality (i%8 const).
// Wave owns 16 q-rows; KV tiles of 64; online softmax fp32;
// P bounced via padded LDS (stride 72 shorts = 144B, 16B-aligned rows).
// ---------------------------------------------------------------------------
__global__ __launch_bounds__(256) void attn_kernel(
    const unsigned short* __restrict__ qkv, const unsigned short* __restrict__ vT,
    unsigned short* __restrict__ vals) {
  const int i = blockIdx.x;
  const int pairIdx = i >> 1, odd = i & 1;
  const int bh = pairIdx & 63, tp = pairIdx >> 6;       // tp 0..7
  const int qt = odd ? (8 + tp) : (7 - tp);             // balanced pairs
  const int b = bh >> 4, h = bh & 15;
  const int t = threadIdx.x, wave = t >> 6, lane = t & 63;
  const int q0 = qt * 64 + wave * 16;
  const int rowLane = lane & 15, grp = lane >> 4;

  __shared__ __attribute__((aligned(16))) unsigned short P_lds[4][16 * 72];

  // Q fragments (A-layout): row = q0 + rowLane, k(=d) = grp*8 (+32)
  const unsigned short* qbase =
      qkv + (size_t)(b * 1024 + q0 + rowLane) * 3072 + h * 64 + grp * 8;
  const bf16x8 aq0 = ldb8(qbase);
  const bf16x8 aq1 = ldb8(qbase + 32);

  f32x4 oacc[4] = {};
  float mrun[4], lrun[4];
  #pragma unroll
  for (int r = 0; r < 4; ++r) { mrun[r] = -1e30f; lrun[r] = 0.f; }

  unsigned short* P = P_lds[wave];

  for (int kt = 0; kt <= qt; ++kt) {
    const int kv0 = kt * 64;
    const bool maskTile = (kt == qt);
    // ---- S = (Q K^T) * 1/8 : 8 MFMA ----
    f32x4 sacc[4];
    #pragma unroll
    for (int nf = 0; nf < 4; ++nf) {
      const unsigned short* kb =
          qkv + (size_t)(b * 1024 + kv0 + nf * 16 + rowLane) * 3072 + 1024 + h * 64 + grp * 8;
      f32x4 z = {0.f, 0.f, 0.f, 0.f};
      z = mfma16(aq0, ldb8(kb), z);
      z = mfma16(aq1, ldb8(kb + 32), z);
      sacc[nf] = z;
    }
    // ---- scale + (diagonal-tile) mask ----
    float p[4][4], mx[4];
    #pragma unroll
    for (int r = 0; r < 4; ++r) {
      #pragma unroll
      for (int nf = 0; nf < 4; ++nf) p[nf][r] = sacc[nf][r] * 0.125f;
    }
    if (maskTile) {
      #pragma unroll
      for (int r = 0; r < 4; ++r) {
        const int qg = q0 + grp * 4 + r;
        #pragma unroll
        for (int nf = 0; nf < 4; ++nf)
          if (kv0 + nf * 16 + rowLane > qg) p[nf][r] = -1e30f;
      }
    }
    // ---- online softmax (row = 16 lanes sharing grp) ----
    #pragma unroll
    for (int r = 0; r < 4; ++r)
      mx[r] = fmaxf(fmaxf(p[0][r], p[1][r]), fmaxf(p[2][r], p[3][r]));
    #pragma unroll
    for (int m = 1; m <= 8; m <<= 1)
      #pragma unroll
      for (int r = 0; r < 4; ++r) mx[r] = fmaxf(mx[r], __shfl_xor(mx[r], m));
    float fac[4], rs[4];
    #pragma unroll
    for (int r = 0; r < 4; ++r) {
      const float mnew = fmaxf(mrun[r], mx[r]);
      fac[r] = __expf(mrun[r] - mnew);
      mrun[r] = mnew;
      float acc = 0.f;
      #pragma unroll
      for (int nf = 0; nf < 4; ++nf) {
        const float e = __expf(p[nf][r] - mnew);
        p[nf][r] = e;
        acc += e;
      }
      rs[r] = acc;
    }
    #pragma unroll
    for (int m = 1; m <= 8; m <<= 1)
      #pragma unroll
      for (int r = 0; r < 4; ++r) rs[r] += __shfl_xor(rs[r], m);
    #pragma unroll
    for (int r = 0; r < 4; ++r) lrun[r] = lrun[r] * fac[r] + rs[r];
    #pragma unroll
    for (int df = 0; df < 4; ++df)
      #pragma unroll
      for (int r = 0; r < 4; ++r) oacc[df][r] *= fac[r];
    // ---- P -> bf16 -> LDS bounce (C-layout -> A-layout) ----
    #pragma unroll
    for (int nf = 0; nf < 4; ++nf)
      #pragma unroll
      for (int r = 0; r < 4; ++r)
        P[(grp * 4 + r) * 72 + nf * 16 + rowLane] = f2bf(p[nf][r]);
    const bf16x8 pa0 = ldb8(&P[rowLane * 72 + grp * 8]);
    const bf16x8 pa1 = ldb8(&P[rowLane * 72 + 32 + grp * 8]);
    // ---- O += P V : 8 MFMA ----
    #pragma unroll
    for (int df = 0; df < 4; ++df) {
      const unsigned short* vb =
          vT + ((size_t)bh * 64 + df * 16 + rowLane) * 1024 + kv0 + grp * 8;
      oacc[df] = mfma16(pa0, ldb8(vb), oacc[df]);
      oacc[df] = mfma16(pa1, ldb8(vb + 32), oacc[df]);
    }
  }
  // ---- epilogue: O / l ----
  #pragma unroll
  for (int df = 0; df < 4; ++df)
    #pragma unroll
    for (int r = 0; r < 4; ++r) {
      const int qg = q0 + grp * 4 + r;
      const float v = oacc[df][r] / lrun[r];
      vals[(size_t)(b * 1024 + qg) * 1024 + h * 64 + df * 16 + rowLane] = f2bf(v);
    }
}

// ---------------------------------------------------------------------------
extern "C" void kernel_launch(void* const* d_in, const int* in_sizes, int n_in,
                              void* d_out, int out_size, void* d_ws, size_t ws_size,
                              hipStream_t stream) {
  (void)in_sizes; (void)n_in; (void)out_size; (void)ws_size;
  const float* inputs = (const float*)d_in[0];
  const float* Wq = (const float*)d_in[1];  const float* bq = (const float*)d_in[2];
  const float* Wk = (const float*)d_in[3];  const float* bk = (const float*)d_in[4];
  const float* Wv = (const float*)d_in[5];  const float* bv = (const float*)d_in[6];
  const float* Wo = (const float*)d_in[7];  const float* bo = (const float*)d_in[8];
  const float* W1 = (const float*)d_in[9];  const float* b1 = (const float*)d_in[10];
  const float* W2 = (const float*)d_in[11]; const float* b2 = (const float*)d_in[12];
  const float* ln_g = (const float*)d_in[13];
  const float* ln_b = (const float*)d_in[14];
  const float* scale_p = (const float*)d_in[15];
  float* xbuf = (float*)d_out;               // fp32 residual stream lives here

  char* w = (char*)d_ws;
  size_t off = 0;
  auto take = [&](size_t bytes) {
    void* p = w + off;
    off = (off + bytes + 255) & ~(size_t)255;
    return p;
  };
  unsigned short* Wqkv_t = (unsigned short*)take((size_t)3072 * 1024 * 2);  // [3072][1024]
  unsigned short* Wo_t   = (unsigned short*)take((size_t)1024 * 1024 * 2);  // [1024][1024]
  unsigned short* W1_t   = (unsigned short*)take((size_t)4096 * 1024 * 2);  // [4096][1024]
  unsigned short* W2_t   = (unsigned short*)take((size_t)1024 * 4096 * 2);  // [1024][4096]
  float*          bqkv   = (float*)take(3072 * 4);
  unsigned short* rbuf   = (unsigned short*)take((size_t)4096 * 1024 * 2);  // LN out
  unsigned short* qkvb   = (unsigned short*)take((size_t)4096 * 3072 * 2);  // q|k|v
  unsigned short* vTb    = (unsigned short*)take((size_t)64 * 64 * 1024 * 2);
  unsigned short* valsb  = (unsigned short*)take((size_t)4096 * 1024 * 2);
  unsigned short* hbuf   = (unsigned short*)take((size_t)4096 * 4096 * 2);  // FFN hidden
  // total ~109 MB

  for (int i = 0; i < 8; ++i) {
    const float* xin = (i == 0) ? inputs : xbuf;
    // weights -> bf16, transposed [N][K]
    transpose_cvt<<<dim3(32, 32), 256, 0, stream>>>(Wq + (size_t)i * 1024 * 1024, Wqkv_t, 1024, 1024);
    transpose_cvt<<<dim3(32, 32), 256, 0, stream>>>(Wk + (size_t)i * 1024 * 1024, Wqkv_t + 1024 * 1024, 1024, 1024);
    transpose_cvt<<<dim3(32, 32), 256, 0, stream>>>(Wv + (size_t)i * 1024 * 1024, Wqkv_t + 2 * 1024 * 1024, 1024, 1024);
    transpose_cvt<<<dim3(32, 32), 256, 0, stream>>>(Wo + (size_t)i * 1024 * 1024, Wo_t, 1024, 1024);
    transpose_cvt<<<dim3(32, 128), 256, 0, stream>>>(W1 + (size_t)i * 1024 * 4096, W1_t, 4096, 1024);
    transpose_cvt<<<dim3(128, 32), 256, 0, stream>>>(W2 + (size_t)i * 4096 * 1024, W2_t, 1024, 4096);
    pack_qkv_bias<<<12, 256, 0, stream>>>(bq + i * 1024, bk + i * 1024, bv + i * 1024, bqkv);
    // attention block
    ln_kernel<0><<<4096, 256, 0, stream>>>(xin, ln_g, ln_b, rbuf);
    gemm_k<0, 128><<<dim3(32, 24), 256, 0, stream>>>(rbuf, Wqkv_t, bqkv, qkvb,
                                                     nullptr, nullptr, nullptr, 3072, 1024);
    v_transpose<<<1024, 256, 0, stream>>>(qkvb, vTb);
    attn_kernel<<<1024, 256, 0, stream>>>(qkvb, vTb, valsb);
    gemm_k<2, 64><<<dim3(32, 16), 256, 0, stream>>>(valsb, Wo_t, bo + i * 1024, nullptr,
                                                    xin, xbuf, scale_p, 1024, 1024);
    // FFN block
    ln_kernel<0><<<4096, 256, 0, stream>>>(xbuf, ln_g, ln_b, rbuf);
    gemm_k<1, 128><<<dim3(32, 32), 256, 0, stream>>>(rbuf, W1_t, b1 + i * 4096, hbuf,
                                                     nullptr, nullptr, nullptr, 4096, 1024);
    gemm_k<2, 64><<<dim3(32, 16), 256, 0, stream>>>(hbuf, W2_t, b2 + i * 1024, nullptr,
                                                    xbuf, xbuf, scale_p, 1024, 4096);
  }
  ln_kernel<1><<<4096, 256, 0, stream>>>(xbuf, ln_g, ln_b, xbuf);  // final LN, in-place
}

// Round 3
// 2658.007 us; speedup vs baseline: 1.1588x; 1.1585x over previous
//
#include <hip/hip_runtime.h>

// ---------------------------------------------------------------------------
// Transformer decoder fwd, bf16-MFMA compute, fp32 residual stream in d_out.
// L=8 B=4 S=1024 D=1024 H=16 dh=64 FC=4096. Threshold 0.1 allows bf16 GEMMs.
// ---------------------------------------------------------------------------

typedef __bf16 bf16x8 __attribute__((ext_vector_type(8)));
typedef float  f32x4  __attribute__((ext_vector_type(4)));

#define DEV static __device__ __forceinline__

DEV unsigned short f2bf(float x) {
  unsigned u = __builtin_bit_cast(unsigned int, x);
  u += 0x7fffu + ((u >> 16) & 1u);          // RNE
  return (unsigned short)(u >> 16);
}

DEV f32x4 mfma16(bf16x8 a, bf16x8 b, f32x4 c) {
  return __builtin_amdgcn_mfma_f32_16x16x32_bf16(a, b, c, 0, 0, 0);
}

DEV bf16x8 ldb8(const unsigned short* p) {
  return *reinterpret_cast<const bf16x8*>(p);
}

DEV void gload_lds16(const unsigned short* g, unsigned short* l) {
  // async global->LDS, 16B/lane; LDS dest = wave-uniform base + lane*16
  __builtin_amdgcn_global_load_lds(
      (const __attribute__((address_space(1))) void*)g,
      (__attribute__((address_space(3))) void*)l, 16, 0, 0);
}

// ---------------------------------------------------------------------------
// fp32 [K][N] -> bf16 [N][K] transposed convert (32x32 LDS tile)
// grid = (K/32, N/32), block = 256
// ---------------------------------------------------------------------------
__global__ void transpose_cvt(const float* __restrict__ src,
                              unsigned short* __restrict__ dst,
                              int srcStride, int dstStride) {
  __shared__ float tile[32][33];
  const int t  = threadIdx.x;
  const int r  = t >> 3;
  const int c4 = (t & 7) << 2;
  const int k  = blockIdx.x * 32 + r;
  const int n0 = blockIdx.y * 32 + c4;
  const float4 v = *reinterpret_cast<const float4*>(src + (size_t)k * srcStride + n0);
  tile[r][c4] = v.x; tile[r][c4 + 1] = v.y; tile[r][c4 + 2] = v.z; tile[r][c4 + 3] = v.w;
  __syncthreads();
  const int n  = blockIdx.y * 32 + r;
  const int k0 = blockIdx.x * 32 + c4;
  ushort4 o;
  o.x = f2bf(tile[c4][r]);     o.y = f2bf(tile[c4 + 1][r]);
  o.z = f2bf(tile[c4 + 2][r]); o.w = f2bf(tile[c4 + 3][r]);
  *reinterpret_cast<ushort4*>(dst + (size_t)n * dstStride + k0) = o;
}

__global__ void pack_qkv_bias(const float* __restrict__ bq, const float* __restrict__ bk,
                              const float* __restrict__ bv, float* __restrict__ out) {
  int i = blockIdx.x * 256 + threadIdx.x;   // 3072
  out[i] = (i < 1024) ? bq[i] : (i < 2048 ? bk[i - 1024] : bv[i - 2048]);
}

// ---------------------------------------------------------------------------
// LayerNorm: one block per row (D=1024, 256 thr x 4 elems). OUTF32: fp32 out
// ---------------------------------------------------------------------------
template <int OUTF32>
__global__ void ln_kernel(const float* x, const float* __restrict__ gam,
                          const float* __restrict__ bet, void* out) {
  const int row = blockIdx.x;
  const int t   = threadIdx.x;
  const float* xr = x + (size_t)row * 1024;
  const float4 v = *reinterpret_cast<const float4*>(xr + t * 4);
  float s  = v.x + v.y + v.z + v.w;
  float ss = v.x * v.x + v.y * v.y + v.z * v.z + v.w * v.w;
  #pragma unroll
  for (int m = 32; m; m >>= 1) { s += __shfl_xor(s, m); ss += __shfl_xor(ss, m); }
  __shared__ float red[8];
  const int wv = t >> 6, ln = t & 63;
  if (ln == 0) { red[wv] = s; red[4 + wv] = ss; }
  __syncthreads();
  s  = red[0] + red[1] + red[2] + red[3];
  ss = red[4] + red[5] + red[6] + red[7];
  const float mean = s * (1.0f / 1024.0f);
  const float var  = ss * (1.0f / 1024.0f) - mean * mean;
  const float rstd = rsqrtf(var + 1e-5f);
  const float4 g  = *reinterpret_cast<const float4*>(gam + t * 4);
  const float4 bb = *reinterpret_cast<const float4*>(bet + t * 4);
  const float y0 = (v.x - mean) * rstd * g.x + bb.x;
  const float y1 = (v.y - mean) * rstd * g.y + bb.y;
  const float y2 = (v.z - mean) * rstd * g.z + bb.z;
  const float y3 = (v.w - mean) * rstd * g.w + bb.w;
  if (OUTF32) {
    float4 o; o.x = y0; o.y = y1; o.z = y2; o.w = y3;
    *reinterpret_cast<float4*>((float*)out + (size_t)row * 1024 + t * 4) = o;
  } else {
    ushort4 o; o.x = f2bf(y0); o.y = f2bf(y1); o.z = f2bf(y2); o.w = f2bf(y3);
    *reinterpret_cast<ushort4*>((unsigned short*)out + (size_t)row * 1024 + t * 4) = o;
  }
}

// ---------------------------------------------------------------------------
// GEMM: C[M][N] = A[M][K](bf16) * Bt[N][K]^T(bf16) + bias.
// m97 structure: 128 x BN tile, BK=32, 4 waves (2x2), global_load_lds x16B.
// MODE 0: bf16 out; MODE 1: gelu(erf) -> bf16; MODE 2: xout = xin + scl*C (f32)
// grid = (M/128, N/BN), block = 256
// ---------------------------------------------------------------------------
template <int MODE, int BN>
__global__ __launch_bounds__(256) void gemm_k(
    const unsigned short* __restrict__ A, const unsigned short* __restrict__ Bt,
    const float* __restrict__ bias, unsigned short* __restrict__ outb,
    const float* xin, float* xout, const float* __restrict__ scale_p,
    int N, int K) {
  constexpr int NI = BN / 32;                 // n-frags per wave
  __shared__ __attribute__((aligned(16))) unsigned short As[128 * 32];
  __shared__ __attribute__((aligned(16))) unsigned short Bs[BN * 32];
  const int t = threadIdx.x, wave = t >> 6, lane = t & 63;
  const int m0 = blockIdx.x * 128, n0 = blockIdx.y * BN;
  const int wm = wave >> 1, wn = wave & 1;

  const int ldr = lane >> 2;                  // row-in-chunk 0..15
  const int kc  = (lane & 3) * 8;             // k offset 0/8/16/24

  const unsigned short* gA0 = A + (size_t)(m0 + wave * 32 + ldr) * K + kc;
  const unsigned short* gA1 = gA0 + (size_t)16 * K;
  unsigned short* lA0 = &As[wave * 1024];
  unsigned short* lA1 = lA0 + 512;

  const unsigned short* gB0;
  const unsigned short* gB1 = nullptr;
  unsigned short *lB0, *lB1 = nullptr;
  if constexpr (BN == 128) {
    gB0 = Bt + (size_t)(n0 + wave * 32 + ldr) * K + kc;
    gB1 = gB0 + (size_t)16 * K;
    lB0 = &Bs[wave * 1024];
    lB1 = lB0 + 512;
  } else {
    gB0 = Bt + (size_t)(n0 + wave * 16 + ldr) * K + kc;
    lB0 = &Bs[wave * 512];
  }

  const int a_off = (wm * 64 + (lane & 15)) * 32 + (lane >> 4) * 8;
  const int b_off = (wn * (BN / 2) + (lane & 15)) * 32 + (lane >> 4) * 8;

  f32x4 acc[4][NI] = {};

  const int nk = K >> 5;
  for (int kt = 0; kt < nk; ++kt) {
    const int ko = kt * 32;
    gload_lds16(gA0 + ko, lA0);
    gload_lds16(gA1 + ko, lA1);
    gload_lds16(gB0 + ko, lB0);
    if constexpr (BN == 128) gload_lds16(gB1 + ko, lB1);
    __syncthreads();                           // waits vmcnt(0): tiles landed
    bf16x8 a[4], bfr[NI];
    #pragma unroll
    for (int i = 0; i < 4; ++i)
      a[i] = *reinterpret_cast<const bf16x8*>(&As[a_off + i * 512]);
    #pragma unroll
    for (int i = 0; i < NI; ++i)
      bfr[i] = *reinterpret_cast<const bf16x8*>(&Bs[b_off + i * 512]);
    #pragma unroll
    for (int mi = 0; mi < 4; ++mi)
      #pragma unroll
      for (int ni = 0; ni < NI; ++ni)
        acc[mi][ni] = mfma16(a[mi], bfr[ni], acc[mi][ni]);
    __syncthreads();                           // compute done before overwrite
  }

  const int mrow = m0 + wm * 64 + (lane >> 4) * 4;
  const int ncol = n0 + wn * (BN / 2) + (lane & 15);
  float scl = 0.f;
  if constexpr (MODE == 2) scl = scale_p[0];
  #pragma unroll
  for (int ni = 0; ni < NI; ++ni) {
    const int n = ncol + ni * 16;
    const float bn = bias[n];
    #pragma unroll
    for (int mi = 0; mi < 4; ++mi) {
      #pragma unroll
      for (int r = 0; r < 4; ++r) {
        const size_t idx = (size_t)(mrow + mi * 16 + r) * N + n;
        float v = acc[mi][ni][r] + bn;
        if constexpr (MODE == 0) {
          outb[idx] = f2bf(v);
        } else if constexpr (MODE == 1) {
          v = 0.5f * v * (1.0f + erff(v * 0.70710678118f));  // exact GELU
          outb[idx] = f2bf(v);
        } else {
          xout[idx] = xin[idx] + scl * v;      // re-zero residual, fp32
        }
      }
    }
  }
}

// ---------------------------------------------------------------------------
// V transpose: qkv v-part [b][s][h][d] -> vT [b][h][d][s] (bf16)
// grid = B*H*(S/64) = 1024, block = 256 (tile: 64 s x 64 d)
// ---------------------------------------------------------------------------
__global__ void v_transpose(const unsigned short* __restrict__ qkv,
                            unsigned short* __restrict__ vT) {
  const int bid = blockIdx.x;
  const int st = bid & 15, bh = bid >> 4;
  const int b = bh >> 4, h = bh & 15;
  const int t = threadIdx.x;
  const int d = t >> 2, s8 = (t & 3) << 4;    // 16 s-positions per thread
  const unsigned short* src =
      qkv + 2048 + (size_t)h * 64 + d + (size_t)(b * 1024 + st * 64 + s8) * 3072;
  alignas(16) unsigned short buf[16];
  #pragma unroll
  for (int i = 0; i < 16; ++i) buf[i] = src[(size_t)i * 3072];
  unsigned short* dst =
      vT + ((size_t)(b * 16 + h) * 64 + d) * 1024 + st * 64 + s8;
  *reinterpret_cast<uint4*>(dst)     = *reinterpret_cast<const uint4*>(buf);
  *reinterpret_cast<uint4*>(dst + 8) = *reinterpret_cast<const uint4*>(buf + 8);
}

// ---------------------------------------------------------------------------
// Flash attention v3, causal. grid = 512 (= 8 pairsets x 64 bh), block = 256.
// Balanced waves: wave w of block (p, bh) owns q-tile PAIR (pp, 63-pp),
// pp = p*4+w, q-tiles are 16 rows. Every pair = exactly 17 KV64-tiles ->
// all 2048 waves identical work, no tail. blockIdx = p*64+bh keeps a head's
// 8 blocks on one XCD (bh%8) -> K/V L2-resident (2MB/XCD).
// Cross-iteration K register prefetch; V loads issued at loop top.
// Math identical to v2 (scale 0.125, __expf, -1e30 mask).
// ---------------------------------------------------------------------------
__global__ __launch_bounds__(256) void attn_kernel(
    const unsigned short* __restrict__ qkv, const unsigned short* __restrict__ vT,
    unsigned short* __restrict__ vals) {
  const int bh = blockIdx.x & 63;
  const int p  = blockIdx.x >> 6;             // 0..7
  const int b = bh >> 4, h = bh & 15;
  const int t = threadIdx.x, wave = t >> 6, lane = t & 63;
  const int pp = p * 4 + wave;                // 0..31
  const int rowLane = lane & 15, grp = lane >> 4;

  __shared__ __attribute__((aligned(16))) unsigned short P_lds[4][16 * 72];
  unsigned short* P = P_lds[wave];

  const unsigned short* qkvB  = qkv + (size_t)b * 1024 * 3072;
  const unsigned short* kBase = qkvB + 1024 + h * 64 + grp * 8;   // +row*3072
  const unsigned short* vHead = vT + (size_t)bh * 64 * 1024;

  #pragma unroll
  for (int u = 0; u < 2; ++u) {
    const int qt = u ? (63 - pp) : pp;        // 16-row q-tile index 0..63
    const int q0 = qt * 16;
    const int nkt = (qt >> 2) + 1;            // KV64 tiles: qt/4 + 1

    const unsigned short* qb = qkvB + (size_t)(q0 + rowLane) * 3072 + h * 64 + grp * 8;
    const bf16x8 aq0 = ldb8(qb);
    const bf16x8 aq1 = ldb8(qb + 32);

    f32x4 oacc[4] = {};
    float mrun[4], lrun[4];
    #pragma unroll
    for (int r = 0; r < 4; ++r) { mrun[r] = -1e30f; lrun[r] = 0.f; }

    // K fragments for kt=0 (prefetched; refilled in-loop after QK^T)
    bf16x8 k0[4], k1[4];
    #pragma unroll
    for (int nf = 0; nf < 4; ++nf) {
      const unsigned short* kb = kBase + (size_t)(nf * 16 + rowLane) * 3072;
      k0[nf] = ldb8(kb); k1[nf] = ldb8(kb + 32);
    }

    for (int kt = 0; kt < nkt; ++kt) {
      const int kv0 = kt * 64;
      // ---- V loads issued early; overlap QK^T + softmax ----
      bf16x8 v0[4], v1[4];
      #pragma unroll
      for (int df = 0; df < 4; ++df) {
        const unsigned short* vb = vHead + (size_t)(df * 16 + rowLane) * 1024 + kv0 + grp * 8;
        v0[df] = ldb8(vb); v1[df] = ldb8(vb + 32);
      }
      // ---- S = (Q K^T) * 1/8 : 8 MFMA ----
      f32x4 sacc[4];
      #pragma unroll
      for (int nf = 0; nf < 4; ++nf) {
        f32x4 z = {0.f, 0.f, 0.f, 0.f};
        z = mfma16(aq0, k0[nf], z);
        z = mfma16(aq1, k1[nf], z);
        sacc[nf] = z;
      }
      // ---- K fragments dead -> prefetch next tile's K into same regs ----
      if (kt + 1 < nkt) {
        #pragma unroll
        for (int nf = 0; nf < 4; ++nf) {
          const unsigned short* kb = kBase + (size_t)(kv0 + 64 + nf * 16 + rowLane) * 3072;
          k0[nf] = ldb8(kb); k1[nf] = ldb8(kb + 32);
        }
      }
      // ---- scale + (diagonal-tile) mask ----
      float pl[4][4], mx[4];
      #pragma unroll
      for (int r = 0; r < 4; ++r) {
        #pragma unroll
        for (int nf = 0; nf < 4; ++nf) pl[nf][r] = sacc[nf][r] * 0.125f;
      }
      if (kt == nkt - 1) {
        #pragma unroll
        for (int r = 0; r < 4; ++r) {
          const int qg = q0 + grp * 4 + r;
          #pragma unroll
          for (int nf = 0; nf < 4; ++nf)
            if (kv0 + nf * 16 + rowLane > qg) pl[nf][r] = -1e30f;
        }
      }
      // ---- online softmax (row = 16 lanes sharing grp) ----
      #pragma unroll
      for (int r = 0; r < 4; ++r)
        mx[r] = fmaxf(fmaxf(pl[0][r], pl[1][r]), fmaxf(pl[2][r], pl[3][r]));
      #pragma unroll
      for (int m = 1; m <= 8; m <<= 1)
        #pragma unroll
        for (int r = 0; r < 4; ++r) mx[r] = fmaxf(mx[r], __shfl_xor(mx[r], m));
      float fac[4], rs[4];
      #pragma unroll
      for (int r = 0; r < 4; ++r) {
        const float mnew = fmaxf(mrun[r], mx[r]);
        fac[r] = __expf(mrun[r] - mnew);
        mrun[r] = mnew;
        float acc = 0.f;
        #pragma unroll
        for (int nf = 0; nf < 4; ++nf) {
          const float e = __expf(pl[nf][r] - mnew);
          pl[nf][r] = e;
          acc += e;
        }
        rs[r] = acc;
      }
      #pragma unroll
      for (int m = 1; m <= 8; m <<= 1)
        #pragma unroll
        for (int r = 0; r < 4; ++r) rs[r] += __shfl_xor(rs[r], m);
      #pragma unroll
      for (int r = 0; r < 4; ++r) lrun[r] = lrun[r] * fac[r] + rs[r];
      #pragma unroll
      for (int df = 0; df < 4; ++df)
        #pragma unroll
        for (int r = 0; r < 4; ++r) oacc[df][r] *= fac[r];
      // ---- P -> bf16 -> LDS bounce (C-layout -> A-layout) ----
      #pragma unroll
      for (int nf = 0; nf < 4; ++nf)
        #pragma unroll
        for (int r = 0; r < 4; ++r)
          P[(grp * 4 + r) * 72 + nf * 16 + rowLane] = f2bf(pl[nf][r]);
      const bf16x8 pa0 = ldb8(&P[rowLane * 72 + grp * 8]);
      const bf16x8 pa1 = ldb8(&P[rowLane * 72 + 32 + grp * 8]);
      // ---- O += P V : 8 MFMA ----
      #pragma unroll
      for (int df = 0; df < 4; ++df) {
        oacc[df] = mfma16(pa0, v0[df], oacc[df]);
        oacc[df] = mfma16(pa1, v1[df], oacc[df]);
      }
    }
    // ---- epilogue: O / l ----
    float rl[4];
    #pragma unroll
    for (int r = 0; r < 4; ++r) rl[r] = 1.0f / lrun[r];
    #pragma unroll
    for (int df = 0; df < 4; ++df)
      #pragma unroll
      for (int r = 0; r < 4; ++r) {
        const int qg = q0 + grp * 4 + r;
        const float v = oacc[df][r] * rl[r];
        vals[(size_t)(b * 1024 + qg) * 1024 + h * 64 + df * 16 + rowLane] = f2bf(v);
      }
  }
}

// ---------------------------------------------------------------------------
extern "C" void kernel_launch(void* const* d_in, const int* in_sizes, int n_in,
                              void* d_out, int out_size, void* d_ws, size_t ws_size,
                              hipStream_t stream) {
  (void)in_sizes; (void)n_in; (void)out_size; (void)ws_size;
  const float* inputs = (const float*)d_in[0];
  const float* Wq = (const float*)d_in[1];  const float* bq = (const float*)d_in[2];
  const float* Wk = (const float*)d_in[3];  const float* bk = (const float*)d_in[4];
  const float* Wv = (const float*)d_in[5];  const float* bv = (const float*)d_in[6];
  const float* Wo = (const float*)d_in[7];  const float* bo = (const float*)d_in[8];
  const float* W1 = (const float*)d_in[9];  const float* b1 = (const float*)d_in[10];
  const float* W2 = (const float*)d_in[11]; const float* b2 = (const float*)d_in[12];
  const float* ln_g = (const float*)d_in[13];
  const float* ln_b = (const float*)d_in[14];
  const float* scale_p = (const float*)d_in[15];
  float* xbuf = (float*)d_out;               // fp32 residual stream lives here

  char* w = (char*)d_ws;
  size_t off = 0;
  auto take = [&](size_t bytes) {
    void* p = w + off;
    off = (off + bytes + 255) & ~(size_t)255;
    return p;
  };
  unsigned short* Wqkv_t = (unsigned short*)take((size_t)3072 * 1024 * 2);  // [3072][1024]
  unsigned short* Wo_t   = (unsigned short*)take((size_t)1024 * 1024 * 2);  // [1024][1024]
  unsigned short* W1_t   = (unsigned short*)take((size_t)4096 * 1024 * 2);  // [4096][1024]
  unsigned short* W2_t   = (unsigned short*)take((size_t)1024 * 4096 * 2);  // [1024][4096]
  float*          bqkv   = (float*)take(3072 * 4);
  unsigned short* rbuf   = (unsigned short*)take((size_t)4096 * 1024 * 2);  // LN out
  unsigned short* qkvb   = (unsigned short*)take((size_t)4096 * 3072 * 2);  // q|k|v
  unsigned short* vTb    = (unsigned short*)take((size_t)64 * 64 * 1024 * 2);
  unsigned short* valsb  = (unsigned short*)take((size_t)4096 * 1024 * 2);
  unsigned short* hbuf   = (unsigned short*)take((size_t)4096 * 4096 * 2);  // FFN hidden
  // total ~109 MB

  for (int i = 0; i < 8; ++i) {
    const float* xin = (i == 0) ? inputs : xbuf;
    // weights -> bf16, transposed [N][K]
    transpose_cvt<<<dim3(32, 32), 256, 0, stream>>>(Wq + (size_t)i * 1024 * 1024, Wqkv_t, 1024, 1024);
    transpose_cvt<<<dim3(32, 32), 256, 0, stream>>>(Wk + (size_t)i * 1024 * 1024, Wqkv_t + 1024 * 1024, 1024, 1024);
    transpose_cvt<<<dim3(32, 32), 256, 0, stream>>>(Wv + (size_t)i * 1024 * 1024, Wqkv_t + 2 * 1024 * 1024, 1024, 1024);
    transpose_cvt<<<dim3(32, 32), 256, 0, stream>>>(Wo + (size_t)i * 1024 * 1024, Wo_t, 1024, 1024);
    transpose_cvt<<<dim3(32, 128), 256, 0, stream>>>(W1 + (size_t)i * 1024 * 4096, W1_t, 4096, 1024);
    transpose_cvt<<<dim3(128, 32), 256, 0, stream>>>(W2 + (size_t)i * 4096 * 1024, W2_t, 1024, 4096);
    pack_qkv_bias<<<12, 256, 0, stream>>>(bq + i * 1024, bk + i * 1024, bv + i * 1024, bqkv);
    // attention block
    ln_kernel<0><<<4096, 256, 0, stream>>>(xin, ln_g, ln_b, rbuf);
    gemm_k<0, 128><<<dim3(32, 24), 256, 0, stream>>>(rbuf, Wqkv_t, bqkv, qkvb,
                                                     nullptr, nullptr, nullptr, 3072, 1024);
    v_transpose<<<1024, 256, 0, stream>>>(qkvb, vTb);
    attn_kernel<<<512, 256, 0, stream>>>(qkvb, vTb, valsb);
    gemm_k<2, 64><<<dim3(32, 16), 256, 0, stream>>>(valsb, Wo_t, bo + i * 1024, nullptr,
                                                    xin, xbuf, scale_p, 1024, 1024);
    // FFN block
    ln_kernel<0><<<4096, 256, 0, stream>>>(xbuf, ln_g, ln_b, rbuf);
    gemm_k<1, 128><<<dim3(32, 32), 256, 0, stream>>>(rbuf, W1_t, b1 + i * 4096, hbuf,
                                                     nullptr, nullptr, nullptr, 4096, 1024);
    gemm_k<2, 64><<<dim3(32, 16), 256, 0, stream>>>(hbuf, W2_t, b2 + i * 1024, nullptr,
                                                    xbuf, xbuf, scale_p, 1024, 4096);
  }
  ln_kernel<1><<<4096, 256, 0, stream>>>(xbuf, ln_g, ln_b, xbuf);  // final LN, in-place
}

// Round 4
// 2271.145 us; speedup vs baseline: 1.3561x; 1.1703x over previous
//
#include <hip/hip_runtime.h>

// ---------------------------------------------------------------------------
// Transformer decoder fwd, bf16-MFMA compute, fp32 residual stream in d_out.
// L=8 B=4 S=1024 D=1024 H=16 dh=64 FC=4096. Threshold 0.1 allows bf16 GEMMs.
// ---------------------------------------------------------------------------

typedef __bf16 bf16x8 __attribute__((ext_vector_type(8)));
typedef float  f32x4  __attribute__((ext_vector_type(4)));

#define DEV static __device__ __forceinline__

DEV unsigned short f2bf(float x) {
  unsigned u = __builtin_bit_cast(unsigned int, x);
  u += 0x7fffu + ((u >> 16) & 1u);          // RNE
  return (unsigned short)(u >> 16);
}

DEV f32x4 mfma16(bf16x8 a, bf16x8 b, f32x4 c) {
  return __builtin_amdgcn_mfma_f32_16x16x32_bf16(a, b, c, 0, 0, 0);
}

DEV bf16x8 ldb8(const unsigned short* p) {
  return *reinterpret_cast<const bf16x8*>(p);
}

DEV void gload_lds16(const unsigned short* g, unsigned short* l) {
  // async global->LDS, 16B/lane; LDS dest = wave-uniform base + lane*16
  __builtin_amdgcn_global_load_lds(
      (const __attribute__((address_space(1))) void*)g,
      (__attribute__((address_space(3))) void*)l, 16, 0, 0);
}

// ---------------------------------------------------------------------------
// fp32 [K][N] -> bf16 [N][K] transposed convert (32x32 LDS tile)
// grid = (K/32, N/32), block = 256
// ---------------------------------------------------------------------------
__global__ void transpose_cvt(const float* __restrict__ src,
                              unsigned short* __restrict__ dst,
                              int srcStride, int dstStride) {
  __shared__ float tile[32][33];
  const int t  = threadIdx.x;
  const int r  = t >> 3;
  const int c4 = (t & 7) << 2;
  const int k  = blockIdx.x * 32 + r;
  const int n0 = blockIdx.y * 32 + c4;
  const float4 v = *reinterpret_cast<const float4*>(src + (size_t)k * srcStride + n0);
  tile[r][c4] = v.x; tile[r][c4 + 1] = v.y; tile[r][c4 + 2] = v.z; tile[r][c4 + 3] = v.w;
  __syncthreads();
  const int n  = blockIdx.y * 32 + r;
  const int k0 = blockIdx.x * 32 + c4;
  ushort4 o;
  o.x = f2bf(tile[c4][r]);     o.y = f2bf(tile[c4 + 1][r]);
  o.z = f2bf(tile[c4 + 2][r]); o.w = f2bf(tile[c4 + 3][r]);
  *reinterpret_cast<ushort4*>(dst + (size_t)n * dstStride + k0) = o;
}

__global__ void pack_qkv_bias(const float* __restrict__ bq, const float* __restrict__ bk,
                              const float* __restrict__ bv, float* __restrict__ out) {
  int i = blockIdx.x * 256 + threadIdx.x;   // 3072
  out[i] = (i < 1024) ? bq[i] : (i < 2048 ? bk[i - 1024] : bv[i - 2048]);
}

// ---------------------------------------------------------------------------
// LayerNorm: one block per row (D=1024, 256 thr x 4 elems). OUTF32: fp32 out
// ---------------------------------------------------------------------------
template <int OUTF32>
__global__ void ln_kernel(const float* x, const float* __restrict__ gam,
                          const float* __restrict__ bet, void* out) {
  const int row = blockIdx.x;
  const int t   = threadIdx.x;
  const float* xr = x + (size_t)row * 1024;
  const float4 v = *reinterpret_cast<const float4*>(xr + t * 4);
  float s  = v.x + v.y + v.z + v.w;
  float ss = v.x * v.x + v.y * v.y + v.z * v.z + v.w * v.w;
  #pragma unroll
  for (int m = 32; m; m >>= 1) { s += __shfl_xor(s, m); ss += __shfl_xor(ss, m); }
  __shared__ float red[8];
  const int wv = t >> 6, ln = t & 63;
  if (ln == 0) { red[wv] = s; red[4 + wv] = ss; }
  __syncthreads();
  s  = red[0] + red[1] + red[2] + red[3];
  ss = red[4] + red[5] + red[6] + red[7];
  const float mean = s * (1.0f / 1024.0f);
  const float var  = ss * (1.0f / 1024.0f) - mean * mean;
  const float rstd = rsqrtf(var + 1e-5f);
  const float4 g  = *reinterpret_cast<const float4*>(gam + t * 4);
  const float4 bb = *reinterpret_cast<const float4*>(bet + t * 4);
  const float y0 = (v.x - mean) * rstd * g.x + bb.x;
  const float y1 = (v.y - mean) * rstd * g.y + bb.y;
  const float y2 = (v.z - mean) * rstd * g.z + bb.z;
  const float y3 = (v.w - mean) * rstd * g.w + bb.w;
  if (OUTF32) {
    float4 o; o.x = y0; o.y = y1; o.z = y2; o.w = y3;
    *reinterpret_cast<float4*>((float*)out + (size_t)row * 1024 + t * 4) = o;
  } else {
    ushort4 o; o.x = f2bf(y0); o.y = f2bf(y1); o.z = f2bf(y2); o.w = f2bf(y3);
    *reinterpret_cast<ushort4*>((unsigned short*)out + (size_t)row * 1024 + t * 4) = o;
  }
}

// ---------------------------------------------------------------------------
// GEMM v2: C[M][N] = A[M][K](bf16) * Bt[N][K]^T(bf16) + bias.
// 128x128 tile, BK=64, 4 waves (2x2, per-wave 64x64), double-buffered LDS
// (2 x 32KB = 64KB -> 2 blocks/CU), XOR-swizzled (chunk ^= row&7, 16B granule)
// via pre-swizzled global source (rule: both-sides-or-neither with gload_lds).
// 2-phase pipeline: stage(next) -> ds_read+MFMA(cur) -> one barrier/iter
// (vmcnt(0) drain sits AFTER the compute phase -> load latency hidden).
// MODE 0: bf16 out; MODE 1: gelu(erf) -> bf16; MODE 2: xout = xin + scl*C (f32)
// grid = (M/128, N/128), block = 256
// ---------------------------------------------------------------------------
template <int MODE>
__global__ __launch_bounds__(256) void gemm2(
    const unsigned short* __restrict__ A, const unsigned short* __restrict__ Bt,
    const float* __restrict__ bias, unsigned short* __restrict__ outb,
    const float* xin, float* xout, const float* __restrict__ scale_p,
    int N, int K) {
  __shared__ __attribute__((aligned(16))) unsigned short lds[2][16384]; // [buf][A 8192 | B 8192]
  const int t = threadIdx.x, wave = t >> 6, lane = t & 63;
  const int m0 = blockIdx.x * 128, n0 = blockIdx.y * 128;
  const int wm = wave >> 1, wn = wave & 1;

  // staging: 1024 16B-chunks per operand per K-tile; chunk c = j*256+wave*64+lane
  // LDS slot (row, ch) holds G[row][ch ^ (row&7)]  (16B-granule XOR swizzle)
  int srow[4], scol[4];
  #pragma unroll
  for (int j = 0; j < 4; ++j) {
    const int c = j * 256 + wave * 64 + lane;
    const int r = c >> 3;
    srow[j] = r;
    scol[j] = ((c & 7) ^ (r & 7)) << 3;     // swizzled source column (shorts)
  }
  const unsigned short* aBase = A + (size_t)m0 * K;
  const unsigned short* bBase = Bt + (size_t)n0 * K;

  // ds_read offsets: frag row uses lane&15 (row&7 == lane&7), k-chunk = lane>>4 (+4)
  const int xk0 = (((lane >> 4)    ) ^ (lane & 7)) << 3;
  const int xk1 = (((lane >> 4) | 4) ^ (lane & 7)) << 3;
  const int arow = (wm * 64 + (lane & 15)) * 64;
  const int brow = (wn * 64 + (lane & 15)) * 64;

  f32x4 acc[4][4] = {};
  const int nk = K >> 6;

  { // prologue: stage K-tile 0 into buf 0
    unsigned short* l = &lds[0][0];
    #pragma unroll
    for (int j = 0; j < 4; ++j) {
      gload_lds16(aBase + (size_t)srow[j] * K + scol[j], l + j * 2048 + wave * 512);
      gload_lds16(bBase + (size_t)srow[j] * K + scol[j], l + 8192 + j * 2048 + wave * 512);
    }
  }
  __syncthreads();

  int cur = 0;
  for (int kt = 0; kt < nk; ++kt) {
    if (kt + 1 < nk) {                       // stage next tile into other buffer
      unsigned short* l = &lds[cur ^ 1][0];
      const int ko = (kt + 1) * 64;
      #pragma unroll
      for (int j = 0; j < 4; ++j) {
        gload_lds16(aBase + (size_t)srow[j] * K + ko + scol[j], l + j * 2048 + wave * 512);
        gload_lds16(bBase + (size_t)srow[j] * K + ko + scol[j], l + 8192 + j * 2048 + wave * 512);
      }
    }
    const unsigned short* l = &lds[cur][0];
    #pragma unroll
    for (int kc = 0; kc < 2; ++kc) {
      const int xk = kc ? xk1 : xk0;
      bf16x8 a[4], b[4];
      #pragma unroll
      for (int mi = 0; mi < 4; ++mi) a[mi] = ldb8(&l[arow + mi * 1024 + xk]);
      #pragma unroll
      for (int ni = 0; ni < 4; ++ni) b[ni] = ldb8(&l[8192 + brow + ni * 1024 + xk]);
      __builtin_amdgcn_s_setprio(1);
      #pragma unroll
      for (int mi = 0; mi < 4; ++mi)
        #pragma unroll
        for (int ni = 0; ni < 4; ++ni)
          acc[mi][ni] = mfma16(a[mi], b[ni], acc[mi][ni]);
      __builtin_amdgcn_s_setprio(0);
    }
    __syncthreads();                         // drains vmcnt AFTER compute phase
    cur ^= 1;
  }

  // epilogue
  const int mrow = m0 + wm * 64 + (lane >> 4) * 4;
  const int ncol = n0 + wn * 64 + (lane & 15);
  float scl = 0.f;
  if constexpr (MODE == 2) scl = scale_p[0];
  #pragma unroll
  for (int ni = 0; ni < 4; ++ni) {
    const int n = ncol + ni * 16;
    const float bn = bias[n];
    #pragma unroll
    for (int mi = 0; mi < 4; ++mi) {
      #pragma unroll
      for (int r = 0; r < 4; ++r) {
        const size_t idx = (size_t)(mrow + mi * 16 + r) * N + n;
        float v = acc[mi][ni][r] + bn;
        if constexpr (MODE == 0) {
          outb[idx] = f2bf(v);
        } else if constexpr (MODE == 1) {
          v = 0.5f * v * (1.0f + erff(v * 0.70710678118f));  // exact GELU
          outb[idx] = f2bf(v);
        } else {
          xout[idx] = xin[idx] + scl * v;    // re-zero residual, fp32
        }
      }
    }
  }
}

// ---------------------------------------------------------------------------
// V transpose: qkv v-part [b][s][h][d] -> vT [b][h][d][s] (bf16)
// grid = B*H*(S/64) = 1024, block = 256 (tile: 64 s x 64 d)
// ---------------------------------------------------------------------------
__global__ void v_transpose(const unsigned short* __restrict__ qkv,
                            unsigned short* __restrict__ vT) {
  const int bid = blockIdx.x;
  const int st = bid & 15, bh = bid >> 4;
  const int b = bh >> 4, h = bh & 15;
  const int t = threadIdx.x;
  const int d = t >> 2, s8 = (t & 3) << 4;    // 16 s-positions per thread
  const unsigned short* src =
      qkv + 2048 + (size_t)h * 64 + d + (size_t)(b * 1024 + st * 64 + s8) * 3072;
  alignas(16) unsigned short buf[16];
  #pragma unroll
  for (int i = 0; i < 16; ++i) buf[i] = src[(size_t)i * 3072];
  unsigned short* dst =
      vT + ((size_t)(b * 16 + h) * 64 + d) * 1024 + st * 64 + s8;
  *reinterpret_cast<uint4*>(dst)     = *reinterpret_cast<const uint4*>(buf);
  *reinterpret_cast<uint4*>(dst + 8) = *reinterpret_cast<const uint4*>(buf + 8);
}

// ---------------------------------------------------------------------------
// Flash attention v3, causal. grid = 512 (= 8 pairsets x 64 bh), block = 256.
// Balanced waves: wave w of block (p, bh) owns q-tile PAIR (pp, 63-pp),
// pp = p*4+w, q-tiles are 16 rows. Every pair = exactly 17 KV64-tiles ->
// all 2048 waves identical work, no tail. blockIdx = p*64+bh keeps a head's
// 8 blocks on one XCD (bh%8) -> K/V L2-resident (2MB/XCD).
// Cross-iteration K register prefetch; V loads issued at loop top.
// ---------------------------------------------------------------------------
__global__ __launch_bounds__(256) void attn_kernel(
    const unsigned short* __restrict__ qkv, const unsigned short* __restrict__ vT,
    unsigned short* __restrict__ vals) {
  const int bh = blockIdx.x & 63;
  const int p  = blockIdx.x >> 6;             // 0..7
  const int b = bh >> 4, h = bh & 15;
  const int t = threadIdx.x, wave = t >> 6, lane = t & 63;
  const int pp = p * 4 + wave;                // 0..31
  const int rowLane = lane & 15, grp = lane >> 4;

  __shared__ __attribute__((aligned(16))) unsigned short P_lds[4][16 * 72];
  unsigned short* P = P_lds[wave];

  const unsigned short* qkvB  = qkv + (size_t)b * 1024 * 3072;
  const unsigned short* kBase = qkvB + 1024 + h * 64 + grp * 8;   // +row*3072
  const unsigned short* vHead = vT + (size_t)bh * 64 * 1024;

  #pragma unroll
  for (int u = 0; u < 2; ++u) {
    const int qt = u ? (63 - pp) : pp;        // 16-row q-tile index 0..63
    const int q0 = qt * 16;
    const int nkt = (qt >> 2) + 1;            // KV64 tiles: qt/4 + 1

    const unsigned short* qb = qkvB + (size_t)(q0 + rowLane) * 3072 + h * 64 + grp * 8;
    const bf16x8 aq0 = ldb8(qb);
    const bf16x8 aq1 = ldb8(qb + 32);

    f32x4 oacc[4] = {};
    float mrun[4], lrun[4];
    #pragma unroll
    for (int r = 0; r < 4; ++r) { mrun[r] = -1e30f; lrun[r] = 0.f; }

    // K fragments for kt=0 (prefetched; refilled in-loop after QK^T)
    bf16x8 k0[4], k1[4];
    #pragma unroll
    for (int nf = 0; nf < 4; ++nf) {
      const unsigned short* kb = kBase + (size_t)(nf * 16 + rowLane) * 3072;
      k0[nf] = ldb8(kb); k1[nf] = ldb8(kb + 32);
    }

    for (int kt = 0; kt < nkt; ++kt) {
      const int kv0 = kt * 64;
      // ---- V loads issued early; overlap QK^T + softmax ----
      bf16x8 v0[4], v1[4];
      #pragma unroll
      for (int df = 0; df < 4; ++df) {
        const unsigned short* vb = vHead + (size_t)(df * 16 + rowLane) * 1024 + kv0 + grp * 8;
        v0[df] = ldb8(vb); v1[df] = ldb8(vb + 32);
      }
      // ---- S = (Q K^T) * 1/8 : 8 MFMA ----
      f32x4 sacc[4];
      #pragma unroll
      for (int nf = 0; nf < 4; ++nf) {
        f32x4 z = {0.f, 0.f, 0.f, 0.f};
        z = mfma16(aq0, k0[nf], z);
        z = mfma16(aq1, k1[nf], z);
        sacc[nf] = z;
      }
      // ---- K fragments dead -> prefetch next tile's K into same regs ----
      if (kt + 1 < nkt) {
        #pragma unroll
        for (int nf = 0; nf < 4; ++nf) {
          const unsigned short* kb = kBase + (size_t)(kv0 + 64 + nf * 16 + rowLane) * 3072;
          k0[nf] = ldb8(kb); k1[nf] = ldb8(kb + 32);
        }
      }
      // ---- scale + (diagonal-tile) mask ----
      float pl[4][4], mx[4];
      #pragma unroll
      for (int r = 0; r < 4; ++r) {
        #pragma unroll
        for (int nf = 0; nf < 4; ++nf) pl[nf][r] = sacc[nf][r] * 0.125f;
      }
      if (kt == nkt - 1) {
        #pragma unroll
        for (int r = 0; r < 4; ++r) {
          const int qg = q0 + grp * 4 + r;
          #pragma unroll
          for (int nf = 0; nf < 4; ++nf)
            if (kv0 + nf * 16 + rowLane > qg) pl[nf][r] = -1e30f;
        }
      }
      // ---- online softmax (row = 16 lanes sharing grp) ----
      #pragma unroll
      for (int r = 0; r < 4; ++r)
        mx[r] = fmaxf(fmaxf(pl[0][r], pl[1][r]), fmaxf(pl[2][r], pl[3][r]));
      #pragma unroll
      for (int m = 1; m <= 8; m <<= 1)
        #pragma unroll
        for (int r = 0; r < 4; ++r) mx[r] = fmaxf(mx[r], __shfl_xor(mx[r], m));
      float fac[4], rs[4];
      #pragma unroll
      for (int r = 0; r < 4; ++r) {
        const float mnew = fmaxf(mrun[r], mx[r]);
        fac[r] = __expf(mrun[r] - mnew);
        mrun[r] = mnew;
        float acc = 0.f;
        #pragma unroll
        for (int nf = 0; nf < 4; ++nf) {
          const float e = __expf(pl[nf][r] - mnew);
          pl[nf][r] = e;
          acc += e;
        }
        rs[r] = acc;
      }
      #pragma unroll
      for (int m = 1; m <= 8; m <<= 1)
        #pragma unroll
        for (int r = 0; r < 4; ++r) rs[r] += __shfl_xor(rs[r], m);
      #pragma unroll
      for (int r = 0; r < 4; ++r) lrun[r] = lrun[r] * fac[r] + rs[r];
      #pragma unroll
      for (int df = 0; df < 4; ++df)
        #pragma unroll
        for (int r = 0; r < 4; ++r) oacc[df][r] *= fac[r];
      // ---- P -> bf16 -> LDS bounce (C-layout -> A-layout) ----
      #pragma unroll
      for (int nf = 0; nf < 4; ++nf)
        #pragma unroll
        for (int r = 0; r < 4; ++r)
          P[(grp * 4 + r) * 72 + nf * 16 + rowLane] = f2bf(pl[nf][r]);
      const bf16x8 pa0 = ldb8(&P[rowLane * 72 + grp * 8]);
      const bf16x8 pa1 = ldb8(&P[rowLane * 72 + 32 + grp * 8]);
      // ---- O += P V : 8 MFMA ----
      #pragma unroll
      for (int df = 0; df < 4; ++df) {
        oacc[df] = mfma16(pa0, v0[df], oacc[df]);
        oacc[df] = mfma16(pa1, v1[df], oacc[df]);
      }
    }
    // ---- epilogue: O / l ----
    float rl[4];
    #pragma unroll
    for (int r = 0; r < 4; ++r) rl[r] = 1.0f / lrun[r];
    #pragma unroll
    for (int df = 0; df < 4; ++df)
      #pragma unroll
      for (int r = 0; r < 4; ++r) {
        const int qg = q0 + grp * 4 + r;
        const float v = oacc[df][r] * rl[r];
        vals[(size_t)(b * 1024 + qg) * 1024 + h * 64 + df * 16 + rowLane] = f2bf(v);
      }
  }
}

// ---------------------------------------------------------------------------
extern "C" void kernel_launch(void* const* d_in, const int* in_sizes, int n_in,
                              void* d_out, int out_size, void* d_ws, size_t ws_size,
                              hipStream_t stream) {
  (void)in_sizes; (void)n_in; (void)out_size; (void)ws_size;
  const float* inputs = (const float*)d_in[0];
  const float* Wq = (const float*)d_in[1];  const float* bq = (const float*)d_in[2];
  const float* Wk = (const float*)d_in[3];  const float* bk = (const float*)d_in[4];
  const float* Wv = (const float*)d_in[5];  const float* bv = (const float*)d_in[6];
  const float* Wo = (const float*)d_in[7];  const float* bo = (const float*)d_in[8];
  const float* W1 = (const float*)d_in[9];  const float* b1 = (const float*)d_in[10];
  const float* W2 = (const float*)d_in[11]; const float* b2 = (const float*)d_in[12];
  const float* ln_g = (const float*)d_in[13];
  const float* ln_b = (const float*)d_in[14];
  const float* scale_p = (const float*)d_in[15];
  float* xbuf = (float*)d_out;               // fp32 residual stream lives here

  char* w = (char*)d_ws;
  size_t off = 0;
  auto take = [&](size_t bytes) {
    void* p = w + off;
    off = (off + bytes + 255) & ~(size_t)255;
    return p;
  };
  unsigned short* Wqkv_t = (unsigned short*)take((size_t)3072 * 1024 * 2);  // [3072][1024]
  unsigned short* Wo_t   = (unsigned short*)take((size_t)1024 * 1024 * 2);  // [1024][1024]
  unsigned short* W1_t   = (unsigned short*)take((size_t)4096 * 1024 * 2);  // [4096][1024]
  unsigned short* W2_t   = (unsigned short*)take((size_t)1024 * 4096 * 2);  // [1024][4096]
  float*          bqkv   = (float*)take(3072 * 4);
  unsigned short* rbuf   = (unsigned short*)take((size_t)4096 * 1024 * 2);  // LN out
  unsigned short* qkvb   = (unsigned short*)take((size_t)4096 * 3072 * 2);  // q|k|v
  unsigned short* vTb    = (unsigned short*)take((size_t)64 * 64 * 1024 * 2);
  unsigned short* valsb  = (unsigned short*)take((size_t)4096 * 1024 * 2);
  unsigned short* hbuf   = (unsigned short*)take((size_t)4096 * 4096 * 2);  // FFN hidden
  // total ~109 MB

  for (int i = 0; i < 8; ++i) {
    const float* xin = (i == 0) ? inputs : xbuf;
    // weights -> bf16, transposed [N][K]
    transpose_cvt<<<dim3(32, 32), 256, 0, stream>>>(Wq + (size_t)i * 1024 * 1024, Wqkv_t, 1024, 1024);
    transpose_cvt<<<dim3(32, 32), 256, 0, stream>>>(Wk + (size_t)i * 1024 * 1024, Wqkv_t + 1024 * 1024, 1024, 1024);
    transpose_cvt<<<dim3(32, 32), 256, 0, stream>>>(Wv + (size_t)i * 1024 * 1024, Wqkv_t + 2 * 1024 * 1024, 1024, 1024);
    transpose_cvt<<<dim3(32, 32), 256, 0, stream>>>(Wo + (size_t)i * 1024 * 1024, Wo_t, 1024, 1024);
    transpose_cvt<<<dim3(32, 128), 256, 0, stream>>>(W1 + (size_t)i * 1024 * 4096, W1_t, 4096, 1024);
    transpose_cvt<<<dim3(128, 32), 256, 0, stream>>>(W2 + (size_t)i * 4096 * 1024, W2_t, 1024, 4096);
    pack_qkv_bias<<<12, 256, 0, stream>>>(bq + i * 1024, bk + i * 1024, bv + i * 1024, bqkv);
    // attention block
    ln_kernel<0><<<4096, 256, 0, stream>>>(xin, ln_g, ln_b, rbuf);
    gemm2<0><<<dim3(32, 24), 256, 0, stream>>>(rbuf, Wqkv_t, bqkv, qkvb,
                                               nullptr, nullptr, nullptr, 3072, 1024);
    v_transpose<<<1024, 256, 0, stream>>>(qkvb, vTb);
    attn_kernel<<<512, 256, 0, stream>>>(qkvb, vTb, valsb);
    gemm2<2><<<dim3(32, 8), 256, 0, stream>>>(valsb, Wo_t, bo + i * 1024, nullptr,
                                              xin, xbuf, scale_p, 1024, 1024);
    // FFN block
    ln_kernel<0><<<4096, 256, 0, stream>>>(xbuf, ln_g, ln_b, rbuf);
    gemm2<1><<<dim3(32, 32), 256, 0, stream>>>(rbuf, W1_t, b1 + i * 4096, hbuf,
                                               nullptr, nullptr, nullptr, 4096, 1024);
    gemm2<2><<<dim3(32, 8), 256, 0, stream>>>(hbuf, W2_t, b2 + i * 1024, nullptr,
                                              xbuf, xbuf, scale_p, 1024, 4096);
  }
  ln_kernel<1><<<4096, 256, 0, stream>>>(xbuf, ln_g, ln_b, xbuf);  // final LN, in-place
}